// Round 7
// baseline (433.184 us; speedup 1.0000x reference)
//
#include <hip/hip_runtime.h>
#include <stdint.h>

typedef __bf16 bf16x8 __attribute__((ext_vector_type(8)));
typedef float f32x4 __attribute__((ext_vector_type(4)));

__device__ __forceinline__ float bf2f(uint16_t u) {
  union { uint32_t i; float f; } v; v.i = ((uint32_t)u) << 16; return v.f;
}
__device__ __forceinline__ uint16_t f2bf(float f) {
  union { float f; uint32_t i; } v; v.f = f;
  uint32_t u = v.i;
  uint32_t r = (u + 0x7FFFu + ((u >> 16) & 1u)) >> 16;
  return (uint16_t)r;
}
// gelu(v) = v * sigmoid(1.5957691*v*(1+0.044715*v^2))  (tanh-form identity).
__device__ __forceinline__ float fast_gelu(float v) {
  float t2 = v * v;
  float pz = 1.0f + 0.044715f * t2;
  float w = -1.5957691216f * v * pz;
  float e = __expf(w);
  return v * __builtin_amdgcn_rcpf(1.0f + e);
}
__device__ __forceinline__ void gld16(uint16_t* l, const uint16_t* g) {
  __builtin_amdgcn_global_load_lds(
      (const __attribute__((address_space(1))) void*)g,
      (__attribute__((address_space(3))) void*)l, 16, 0, 0);
}

// ---------------------------------------------------------------------------
// Kernel 0: convert fc1/fc2 weights fp32 -> bf16 into workspace.
// ---------------------------------------------------------------------------
__global__ __launch_bounds__(256) void cvt_weights_kernel(
    const float* __restrict__ fc1, const float* __restrict__ fc2,
    uint16_t* __restrict__ fc1b, uint16_t* __restrict__ fc2b)
{
  int i = (blockIdx.x * 256 + threadIdx.x) * 4;
  if (i < 262144) {
    float4 a = *(const float4*)(fc1 + i);
    ushort4 o;
    o.x = f2bf(a.x); o.y = f2bf(a.y); o.z = f2bf(a.z); o.w = f2bf(a.w);
    *(ushort4*)(fc1b + i) = o;
  } else {
    int j = i - 262144;
    float4 a = *(const float4*)(fc2 + j);
    ushort4 o;
    o.x = f2bf(a.x); o.y = f2bf(a.y); o.z = f2bf(a.z); o.w = f2bf(a.w);
    *(ushort4*)(fc2b + j) = o;
  }
}

// ---------------------------------------------------------------------------
// Kernel 1 (v2): NeoCell + BatchNorm(eval).  x: NCHW fp32 -> y1 NHWC bf16.
// (unchanged — verified)
// ---------------------------------------------------------------------------
__global__ __launch_bounds__(128) void neocell_bn_kernel(
    const float* __restrict__ x,
    const float* __restrict__ wa1, const float* __restrict__ wb1,
    const float* __restrict__ wa2, const float* __restrict__ wb2,
    const float* __restrict__ bnw, const float* __restrict__ bnb,
    const float* __restrict__ bnm, const float* __restrict__ bnv,
    uint16_t* __restrict__ y1)
{
  __shared__ uint16_t lx[64 * 226];   // 28928 B
  const int t = threadIdx.x;          // 0..127
  const int strip = blockIdx.x;       // 0..13 (4-row strips)
  const int b = blockIdx.y;           // 0..31
  const int grp = blockIdx.z;         // 0..3 (64-channel group)
  const int h0 = strip * 4;

  for (int i = 0; i < 28; ++i) {
    int l = t + i * 128;              // 0..3583
    int c = l / 56;                   // channel 0..63
    int r = l - c * 56;               // float4 index 0..55 within strip
    const float* g = x + (size_t)(b * 256 + grp * 64 + c) * 3136
                       + h0 * 56 + r * 4;
    float4 v = *(const float4*)g;
    ushort4 o;
    o.x = f2bf(v.x); o.y = f2bf(v.y); o.z = f2bf(v.z); o.w = f2bf(v.w);
    *(ushort4*)(lx + c * 226 + r * 4) = o;
  }
  __syncthreads();

  const int c = t & 63;               // channel within group
  const int p = t >> 6;               // 0,1: row-block (k2) / col parity (k4)
  const int cg = grp * 64 + c;        // global channel

  const float sc = bnw[cg] * rsqrtf(bnv[cg] + 1e-5f);
  const float sh = bnb[cg] - bnm[cg] * sc;
  const size_t pgbase = (size_t)b * 3136 + (size_t)h0 * 56;
  const uint16_t* lc0 = lx + c * 226;

  if (grp < 2) {
    float A[2][2], Bm[2][2];
#pragma unroll
    for (int i = 0; i < 2; ++i)
#pragma unroll
      for (int j = 0; j < 2; ++j) {
        A[i][j]  = wa1[cg * 4 + i * 2 + j];
        Bm[i][j] = wb1[cg * 4 + i * 2 + j];
      }
    for (int m = 0; m < 28; ++m) {
      const uint16_t* lc = lc0 + (2 * p) * 56 + m * 2;
      uint32_t w0 = *(const uint32_t*)lc;
      uint32_t w1 = *(const uint32_t*)(lc + 56);
      float X[2][2];
      X[0][0] = bf2f((uint16_t)w0); X[0][1] = bf2f((uint16_t)(w0 >> 16));
      X[1][0] = bf2f((uint16_t)w1); X[1][1] = bf2f((uint16_t)(w1 >> 16));
      float T[2][2];
#pragma unroll
      for (int pp = 0; pp < 2; ++pp)
#pragma unroll
        for (int j = 0; j < 2; ++j)
          T[pp][j] = A[pp][0] * X[0][j] + A[pp][1] * X[1][j];
#pragma unroll
      for (int pp = 0; pp < 2; ++pp)
#pragma unroll
        for (int q = 0; q < 2; ++q) {
          float O = (T[pp][0] * Bm[0][q] + T[pp][1] * Bm[1][q]) * sc + sh;
          size_t pg = pgbase + (size_t)(2 * p + pp) * 56 + (m * 2 + q);
          y1[pg * 256 + cg] = f2bf(O);
        }
    }
  } else {
    const int ck = cg - 128;          // index into wa2/wb2
    float A[4][4], Bm[4][4];
#pragma unroll
    for (int i = 0; i < 4; ++i)
#pragma unroll
      for (int j = 0; j < 4; ++j) {
        A[i][j]  = wa2[ck * 16 + i * 4 + j];
        Bm[i][j] = wb2[ck * 16 + i * 4 + j];
      }
    for (int mm = 0; mm < 7; ++mm) {
      int m = 2 * mm + p;
      float X[4][4];
#pragma unroll
      for (int i = 0; i < 4; ++i) {
        const uint16_t* lc = lc0 + i * 56 + m * 4;
        uint32_t w0 = *(const uint32_t*)lc;
        uint32_t w1 = *(const uint32_t*)(lc + 2);
        X[i][0] = bf2f((uint16_t)w0); X[i][1] = bf2f((uint16_t)(w0 >> 16));
        X[i][2] = bf2f((uint16_t)w1); X[i][3] = bf2f((uint16_t)(w1 >> 16));
      }
      float T[4][4];
#pragma unroll
      for (int pp = 0; pp < 4; ++pp)
#pragma unroll
        for (int j = 0; j < 4; ++j)
          T[pp][j] = A[pp][0] * X[0][j] + A[pp][1] * X[1][j]
                   + A[pp][2] * X[2][j] + A[pp][3] * X[3][j];
#pragma unroll
      for (int pp = 0; pp < 4; ++pp)
#pragma unroll
        for (int q = 0; q < 4; ++q) {
          float O = (T[pp][0] * Bm[0][q] + T[pp][1] * Bm[1][q]
                   + T[pp][2] * Bm[2][q] + T[pp][3] * Bm[3][q]) * sc + sh;
          size_t pg = pgbase + (size_t)pp * 56 + (m * 4 + q);
          y1[pg * 256 + cg] = f2bf(O);
        }
    }
  }
}

// ---------------------------------------------------------------------------
// GEMM (pipelined v4): C[row][col] = sum_k A[row][k] * B[col][k].
// 128x128 tile, BK=32, 4 waves 2x2, global_load_lds width=16.
// T4 counted-vmcnt, 3-buffer rotation, 2-tile-deep prefetch.
// v3's NaN was a cross-wave RAW race: vmcnt is PER-WAVE, and each tile's LDS
// image is written by all 4 waves' loads — so the collective-completion fact
// must be established by wait-THEN-barrier (m201 ordering), not barrier-then-
// wait (v3). Per step:
//   stage(t+2) -> S[nxt]   (12 outstanding)
//   s_waitcnt vmcnt(8)     (own tile-t loads retired, oldest-first)
//   s_barrier              (=> ALL waves' tile-t loads retired)
//   ds_read S[cur] + MFMA  (RAW-safe)
//   s_barrier              (reads done via MFMA data-dep => WAR-safe for the
//                           next iter's stage into this buffer)
// No vmcnt(0) in the loop. Tail stages clamped in-bounds, never consumed.
// EPI1 reuses LDS only after a full __syncthreads (vmcnt-0 drain).
// XCD-chunk swizzle kept (bijective, n%8==0 for both grids).
// ---------------------------------------------------------------------------
template <int KD, int EPI>
__global__ __launch_bounds__(256) void gemm_bt_kernel(
    const uint16_t* __restrict__ A,     // rows x KD, row-major bf16
    const uint16_t* __restrict__ Bw,    // cols x KD, row-major bf16
    uint16_t* __restrict__ Cb16,        // EPI0 output (bf16)
    float* __restrict__ Cf32,           // EPI1 output (fp32 NCHW)
    const float* __restrict__ Xres,     // EPI1: residual (NCHW fp32)
    int chunk_pix0)                     // EPI1: global pixel offset of chunk
{
  __shared__ uint16_t lds[24576];       // 3 stages: S[i] at i*8192 (A|B 4096)

  const int tid = threadIdx.x;
  const int lane = tid & 63;
  const int wid = tid >> 6;
  const int wm = wid & 1;
  const int wn = wid >> 1;
  const int fm = lane & 15;             // MFMA row/col within 16
  const int fq = lane >> 4;             // quad

  // XCD-chunk swizzle (T1). lid = hw linear id (x fastest).
  uint32_t nx = gridDim.x;
  uint32_t n = nx * gridDim.y;
  uint32_t lid = blockIdx.y * nx + blockIdx.x;
  uint32_t bx, by;
  if ((n & 7u) == 0u) {
    uint32_t w = (lid & 7u) * (n >> 3) + (lid >> 3);
    bx = w & (nx - 1u);                 // nx is 2 or 8 (pow2)
    by = w / nx;
  } else {
    bx = blockIdx.x; by = blockIdx.y;
  }

  const size_t arow0 = (size_t)by * 128;   // pixel-tile base
  const size_t brow0 = (size_t)bx * 128;   // col-block base

  f32x4 acc[4][4];
#pragma unroll
  for (int i = 0; i < 4; ++i)
#pragma unroll
    for (int j = 0; j < 4; ++j) { f32x4 z = {0.f, 0.f, 0.f, 0.f}; acc[i][j] = z; }

  const int q0 = tid, q1 = tid + 256;
  const int r0 = q0 >> 2, kk0 = q0 & 3;
  const int r1 = q1 >> 2, kk1 = q1 & 3;
  const uint16_t* a0 = A + (arow0 + r0) * KD + kk0 * 8;
  const uint16_t* a1 = A + (arow0 + r1) * KD + kk1 * 8;
  const uint16_t* b0 = Bw + (brow0 + r0) * KD + kk0 * 8;
  const uint16_t* b1 = Bw + (brow0 + r1) * KD + kk1 * 8;

  constexpr int NT = KD / 32;           // 8 (GEMM1) or 32 (GEMM2)

  // Stage tile kt (4 VMEM instrs/wave) into stage buffer S.
  auto stage = [&](uint16_t* S, int kt) {
    const int ke = kt * 32;
    gld16(S + q0 * 8, a0 + ke);
    gld16(S + q1 * 8, a1 + ke);
    gld16(S + 4096 + q0 * 8, b0 + ke);
    gld16(S + 4096 + q1 * 8, b1 + ke);
  };

  // Prologue: 2-deep prefetch (8 VMEM outstanding).
  stage(lds, 0);
  stage(lds + 8192, 1);

  int cur = 0, nxt = 2;
#pragma unroll 1
  for (int t = 0; t < NT; ++t) {
    int kn = t + 2; if (kn > NT - 1) kn = NT - 1;   // tail clamp (in-bounds)
    stage(lds + nxt * 8192, kn);        // outstanding: 12
    asm volatile("s_waitcnt vmcnt(8)" ::: "memory"); // own tile-t retired
    __builtin_amdgcn_s_barrier();       // ALL waves' tile-t loads retired
    asm volatile("" ::: "memory");

    const uint16_t* CA = lds + cur * 8192;
    const uint16_t* CB = CA + 4096;
    bf16x8 af[4], bfr[4];
#pragma unroll
    for (int mt = 0; mt < 4; ++mt)
      af[mt] = *(const bf16x8*)(const void*)
               (CA + (wm * 64 + mt * 16 + fm) * 32 + fq * 8);
#pragma unroll
    for (int nt = 0; nt < 4; ++nt)
      bfr[nt] = *(const bf16x8*)(const void*)
                (CB + (wn * 64 + nt * 16 + fm) * 32 + fq * 8);
#pragma unroll
    for (int mt = 0; mt < 4; ++mt)
#pragma unroll
      for (int nt = 0; nt < 4; ++nt)
        acc[mt][nt] = __builtin_amdgcn_mfma_f32_16x16x32_bf16(
            af[mt], bfr[nt], acc[mt][nt], 0, 0, 0);

    asm volatile("" ::: "memory");
    __builtin_amdgcn_s_barrier();       // reads of S[cur] done in all waves
    asm volatile("" ::: "memory");      // -> next iter may restage it (WAR)

    cur = (cur == 2) ? 0 : cur + 1;
    nxt = (nxt == 2) ? 0 : nxt + 1;
  }

  if (EPI == 0) {
    // fast GELU -> h, row-major (rows x 1024) bf16.
    // D layout: col=lane&15, row=fq*4+r (m89/m91 verified).
#pragma unroll
    for (int mt = 0; mt < 4; ++mt) {
      const size_t rb = arow0 + wm * 64 + mt * 16 + fq * 4;
#pragma unroll
      for (int nt = 0; nt < 4; ++nt) {
        const size_t n2 = brow0 + wn * 64 + nt * 16 + fm;
#pragma unroll
        for (int r = 0; r < 4; ++r)
          Cb16[(rb + r) * 1024 + n2] = f2bf(fast_gelu(acc[mt][nt][r]));
      }
    }
  } else {
    // Transpose through LDS -> pixel-contiguous NCHW fp32 stores + residual.
    __syncthreads();                    // drains vmcnt(0): dup stages landed
#pragma unroll
    for (int mt = 0; mt < 4; ++mt) {
      int mbase = wm * 64 + mt * 16 + fq * 4;     // pixel within tile
#pragma unroll
      for (int nt = 0; nt < 4; ++nt) {
        int nn = wn * 64 + nt * 16 + fm;          // channel within tile
#pragma unroll
        for (int r = 0; r < 4; ++r)
          lds[nn * 130 + mbase + r] = f2bf(acc[mt][nt][r]);
      }
    }
    __syncthreads();
    const int pl0 = tid & 31;
    const int cw = tid >> 5;
#pragma unroll
    for (int it = 0; it < 16; ++it) {
      int ch = cw + it * 8;                        // channel within tile
      int cgl = (int)brow0 + ch;                   // global channel
#pragma unroll
      for (int e = 0; e < 4; ++e) {
        int pl = pl0 + e * 32;                     // pixel within tile
        uint32_t pg = (uint32_t)chunk_pix0 + by * 128u + (uint32_t)pl;
        uint32_t bimg = pg / 3136u;
        uint32_t rem = pg - bimg * 3136u;
        size_t addr = ((size_t)bimg * 256 + cgl) * 3136 + rem;
        Cf32[addr] = bf2f(lds[ch * 130 + pl]) + Xres[addr];
      }
    }
  }
}

// ---------------------------------------------------------------------------
// Launch: cvt weights -> neocell -> y1 (ws). Then (single pass if ws allows):
//   GEMM1 (K=256)  y1 @ fc1^T -> gelu -> h (bf16, ws)
//   GEMM2 (K=1024) h @ fc2^T + x -> out (fp32 NCHW)
// ---------------------------------------------------------------------------
extern "C" void kernel_launch(void* const* d_in, const int* in_sizes, int n_in,
                              void* d_out, int out_size, void* d_ws,
                              size_t ws_size, hipStream_t stream)
{
  const float* x   = (const float*)d_in[0];
  const float* wa1 = (const float*)d_in[1];
  const float* wb1 = (const float*)d_in[2];
  const float* wa2 = (const float*)d_in[3];
  const float* wb2 = (const float*)d_in[4];
  const float* bnw = (const float*)d_in[5];
  const float* bnb = (const float*)d_in[6];
  const float* bnm = (const float*)d_in[7];
  const float* bnv = (const float*)d_in[8];
  const float* fc1 = (const float*)d_in[9];
  const float* fc2 = (const float*)d_in[10];
  float* out = (float*)d_out;

  uint16_t* fc1b = (uint16_t*)d_ws;                 // 512 KB
  uint16_t* fc2b = fc1b + 262144;                   // 512 KB
  uint16_t* y1 = fc2b + 262144;                     // 51.4 MB
  const size_t y1_elems = (size_t)100352 * 256;
  uint16_t* h = y1 + y1_elems;

  const long tiles_total = 784;                     // 100352 / 128
  const size_t fixed_bytes = (size_t)262144 * 4 + y1_elems * 2;
  long tiles_chunk = 1;
  if (ws_size > fixed_bytes + 262144) {
    tiles_chunk = (long)((ws_size - fixed_bytes) / (128ul * 1024ul * 2ul));
    if (tiles_chunk > tiles_total) tiles_chunk = tiles_total;
    if (tiles_chunk < 1) tiles_chunk = 1;
  }

  cvt_weights_kernel<<<512, 256, 0, stream>>>(fc1, fc2, fc1b, fc2b);
  neocell_bn_kernel<<<dim3(14, 32, 4), 128, 0, stream>>>(
      x, wa1, wb1, wa2, wb2, bnw, bnb, bnm, bnv, y1);

  for (long t0 = 0; t0 < tiles_total; t0 += tiles_chunk) {
    long T = tiles_total - t0;
    if (T > tiles_chunk) T = tiles_chunk;
    gemm_bt_kernel<256, 0><<<dim3(8, (uint32_t)T), 256, 0, stream>>>(
        y1 + (size_t)t0 * 128 * 256, fc1b, h, nullptr, nullptr, 0);
    gemm_bt_kernel<1024, 1><<<dim3(2, (uint32_t)T), 256, 0, stream>>>(
        h, fc2b, nullptr, out, x, (int)(t0 * 128));
  }
}

// Round 8
// 419.851 us; speedup vs baseline: 1.0318x; 1.0318x over previous
//
#include <hip/hip_runtime.h>
#include <stdint.h>

typedef __bf16 bf16x8 __attribute__((ext_vector_type(8)));
typedef float f32x4 __attribute__((ext_vector_type(4)));

__device__ __forceinline__ float bf2f(uint16_t u) {
  union { uint32_t i; float f; } v; v.i = ((uint32_t)u) << 16; return v.f;
}
__device__ __forceinline__ uint16_t f2bf(float f) {
  union { float f; uint32_t i; } v; v.f = f;
  uint32_t u = v.i;
  uint32_t r = (u + 0x7FFFu + ((u >> 16) & 1u)) >> 16;
  return (uint16_t)r;
}
// gelu(v) = v * sigmoid(1.5957691*v*(1+0.044715*v^2))  (tanh-form identity).
__device__ __forceinline__ float fast_gelu(float v) {
  float t2 = v * v;
  float pz = 1.0f + 0.044715f * t2;
  float w = -1.5957691216f * v * pz;
  float e = __expf(w);
  return v * __builtin_amdgcn_rcpf(1.0f + e);
}
__device__ __forceinline__ void gld16(uint16_t* l, const uint16_t* g) {
  __builtin_amdgcn_global_load_lds(
      (const __attribute__((address_space(1))) void*)g,
      (__attribute__((address_space(3))) void*)l, 16, 0, 0);
}

// ---------------------------------------------------------------------------
// Kernel 0: convert fc1/fc2 weights fp32 -> bf16 into workspace.
// ---------------------------------------------------------------------------
__global__ __launch_bounds__(256) void cvt_weights_kernel(
    const float* __restrict__ fc1, const float* __restrict__ fc2,
    uint16_t* __restrict__ fc1b, uint16_t* __restrict__ fc2b)
{
  int i = (blockIdx.x * 256 + threadIdx.x) * 4;
  if (i < 262144) {
    float4 a = *(const float4*)(fc1 + i);
    ushort4 o;
    o.x = f2bf(a.x); o.y = f2bf(a.y); o.z = f2bf(a.z); o.w = f2bf(a.w);
    *(ushort4*)(fc1b + i) = o;
  } else {
    int j = i - 262144;
    float4 a = *(const float4*)(fc2 + j);
    ushort4 o;
    o.x = f2bf(a.x); o.y = f2bf(a.y); o.z = f2bf(a.z); o.w = f2bf(a.w);
    *(ushort4*)(fc2b + j) = o;
  }
}

// ---------------------------------------------------------------------------
// Kernel 1 (v2): NeoCell + BatchNorm(eval).  x: NCHW fp32 -> y1 NHWC bf16.
// (unchanged — verified)
// ---------------------------------------------------------------------------
__global__ __launch_bounds__(128) void neocell_bn_kernel(
    const float* __restrict__ x,
    const float* __restrict__ wa1, const float* __restrict__ wb1,
    const float* __restrict__ wa2, const float* __restrict__ wb2,
    const float* __restrict__ bnw, const float* __restrict__ bnb,
    const float* __restrict__ bnm, const float* __restrict__ bnv,
    uint16_t* __restrict__ y1)
{
  __shared__ uint16_t lx[64 * 226];   // 28928 B
  const int t = threadIdx.x;          // 0..127
  const int strip = blockIdx.x;       // 0..13 (4-row strips)
  const int b = blockIdx.y;           // 0..31
  const int grp = blockIdx.z;         // 0..3 (64-channel group)
  const int h0 = strip * 4;

  for (int i = 0; i < 28; ++i) {
    int l = t + i * 128;              // 0..3583
    int c = l / 56;                   // channel 0..63
    int r = l - c * 56;               // float4 index 0..55 within strip
    const float* g = x + (size_t)(b * 256 + grp * 64 + c) * 3136
                       + h0 * 56 + r * 4;
    float4 v = *(const float4*)g;
    ushort4 o;
    o.x = f2bf(v.x); o.y = f2bf(v.y); o.z = f2bf(v.z); o.w = f2bf(v.w);
    *(ushort4*)(lx + c * 226 + r * 4) = o;
  }
  __syncthreads();

  const int c = t & 63;               // channel within group
  const int p = t >> 6;               // 0,1: row-block (k2) / col parity (k4)
  const int cg = grp * 64 + c;        // global channel

  const float sc = bnw[cg] * rsqrtf(bnv[cg] + 1e-5f);
  const float sh = bnb[cg] - bnm[cg] * sc;
  const size_t pgbase = (size_t)b * 3136 + (size_t)h0 * 56;
  const uint16_t* lc0 = lx + c * 226;

  if (grp < 2) {
    float A[2][2], Bm[2][2];
#pragma unroll
    for (int i = 0; i < 2; ++i)
#pragma unroll
      for (int j = 0; j < 2; ++j) {
        A[i][j]  = wa1[cg * 4 + i * 2 + j];
        Bm[i][j] = wb1[cg * 4 + i * 2 + j];
      }
    for (int m = 0; m < 28; ++m) {
      const uint16_t* lc = lc0 + (2 * p) * 56 + m * 2;
      uint32_t w0 = *(const uint32_t*)lc;
      uint32_t w1 = *(const uint32_t*)(lc + 56);
      float X[2][2];
      X[0][0] = bf2f((uint16_t)w0); X[0][1] = bf2f((uint16_t)(w0 >> 16));
      X[1][0] = bf2f((uint16_t)w1); X[1][1] = bf2f((uint16_t)(w1 >> 16));
      float T[2][2];
#pragma unroll
      for (int pp = 0; pp < 2; ++pp)
#pragma unroll
        for (int j = 0; j < 2; ++j)
          T[pp][j] = A[pp][0] * X[0][j] + A[pp][1] * X[1][j];
#pragma unroll
      for (int pp = 0; pp < 2; ++pp)
#pragma unroll
        for (int q = 0; q < 2; ++q) {
          float O = (T[pp][0] * Bm[0][q] + T[pp][1] * Bm[1][q]) * sc + sh;
          size_t pg = pgbase + (size_t)(2 * p + pp) * 56 + (m * 2 + q);
          y1[pg * 256 + cg] = f2bf(O);
        }
    }
  } else {
    const int ck = cg - 128;          // index into wa2/wb2
    float A[4][4], Bm[4][4];
#pragma unroll
    for (int i = 0; i < 4; ++i)
#pragma unroll
      for (int j = 0; j < 4; ++j) {
        A[i][j]  = wa2[ck * 16 + i * 4 + j];
        Bm[i][j] = wb2[ck * 16 + i * 4 + j];
      }
    for (int mm = 0; mm < 7; ++mm) {
      int m = 2 * mm + p;
      float X[4][4];
#pragma unroll
      for (int i = 0; i < 4; ++i) {
        const uint16_t* lc = lc0 + i * 56 + m * 4;
        uint32_t w0 = *(const uint32_t*)lc;
        uint32_t w1 = *(const uint32_t*)(lc + 2);
        X[i][0] = bf2f((uint16_t)w0); X[i][1] = bf2f((uint16_t)(w0 >> 16));
        X[i][2] = bf2f((uint16_t)w1); X[i][3] = bf2f((uint16_t)(w1 >> 16));
      }
      float T[4][4];
#pragma unroll
      for (int pp = 0; pp < 4; ++pp)
#pragma unroll
        for (int j = 0; j < 4; ++j)
          T[pp][j] = A[pp][0] * X[0][j] + A[pp][1] * X[1][j]
                   + A[pp][2] * X[2][j] + A[pp][3] * X[3][j];
#pragma unroll
      for (int pp = 0; pp < 4; ++pp)
#pragma unroll
        for (int q = 0; q < 4; ++q) {
          float O = (T[pp][0] * Bm[0][q] + T[pp][1] * Bm[1][q]
                   + T[pp][2] * Bm[2][q] + T[pp][3] * Bm[3][q]) * sc + sh;
          size_t pg = pgbase + (size_t)pp * 56 + (m * 4 + q);
          y1[pg * 256 + cg] = f2bf(O);
        }
    }
  }
}

// ---------------------------------------------------------------------------
// GEMM (pipelined v5): C[row][col] = sum_k A[row][k] * B[col][k].
// 128x128 tile, BK=64, 4 waves 2x2, global_load_lds width=16.
// Sync structure = r5-verified dbuf (stage next -> ds_read cur -> MFMA ->
// __syncthreads). BK=64 halves barrier count and doubles MFMA per phase
// (32) so compute covers the staged loads' latency.
// Bank-floor swizzle (coupled to BK=64): LDS row stride = 128 B = bank wrap,
// so naive b128 reads serialize 2x the wave floor. Fix: LDS dest stays
// LINEAR (gld_lds requirement), per-lane GLOBAL source slot is permuted
// kk -> kk^(row&7); reads use slot (h*4+fq)^(fm&7). XOR = involution on
// both sides (rule #21); 8 exclusive bank-starts x 8 lanes = b128 floor.
// XCD-chunk swizzle kept (bijective, n%8==0 for both grids).
// EPI 0: fast GELU -> h (rows x 1024 bf16).
// EPI 1: LDS-transpose epilogue -> NCHW fp32 out + fused fp32 residual.
// ---------------------------------------------------------------------------
template <int KD, int EPI>
__global__ __launch_bounds__(256) void gemm_bt_kernel(
    const uint16_t* __restrict__ A,     // rows x KD, row-major bf16
    const uint16_t* __restrict__ Bw,    // cols x KD, row-major bf16
    uint16_t* __restrict__ Cb16,        // EPI0 output (bf16)
    float* __restrict__ Cf32,           // EPI1 output (fp32 NCHW)
    const float* __restrict__ Xres,     // EPI1: residual (NCHW fp32)
    int chunk_pix0)                     // EPI1: global pixel offset of chunk
{
  __shared__ uint16_t lds[32768];       // dbuf: A0|B0|A1|B1, 8192 u16 each
  uint16_t* A0 = lds;                   // (64 KB; epilogue reuses region)
  uint16_t* B0 = lds + 8192;
  uint16_t* A1 = lds + 16384;
  uint16_t* B1 = lds + 24576;

  const int tid = threadIdx.x;
  const int lane = tid & 63;
  const int wid = tid >> 6;
  const int wm = wid & 1;
  const int wn = wid >> 1;
  const int fm = lane & 15;             // MFMA row/col within 16
  const int fq = lane >> 4;             // quad

  // XCD-chunk swizzle (T1). lid = hw linear id (x fastest).
  uint32_t nx = gridDim.x;
  uint32_t n = nx * gridDim.y;
  uint32_t lid = blockIdx.y * nx + blockIdx.x;
  uint32_t bx, by;
  if ((n & 7u) == 0u) {
    uint32_t w = (lid & 7u) * (n >> 3) + (lid >> 3);
    bx = w & (nx - 1u);                 // nx is 2 or 8 (pow2)
    by = w / nx;
  } else {
    bx = blockIdx.x; by = blockIdx.y;
  }

  const size_t arow0 = (size_t)by * 128;   // pixel-tile base
  const size_t brow0 = (size_t)bx * 128;   // col-block base

  f32x4 acc[4][4];
#pragma unroll
  for (int i = 0; i < 4; ++i)
#pragma unroll
    for (int j = 0; j < 4; ++j) { f32x4 z = {0.f, 0.f, 0.f, 0.f}; acc[i][j] = z; }

  // Stage one BK=64 tile (8 gld16/thread). LDS linear in q; global slot
  // pre-swizzled kk^(r&7) so swizzled reads see the right data.
  auto stage = [&](uint16_t* SA, uint16_t* SB, int kt) {
    const int ke = kt * 64;
#pragma unroll
    for (int s = 0; s < 4; ++s) {
      int q = tid + s * 256;            // 0..1023: r = q>>3, kk = q&7
      int r = q >> 3;
      int kkg = (q & 7) ^ (r & 7);      // involution
      gld16(SA + q * 8, A + (arow0 + r) * KD + ke + kkg * 8);
      gld16(SB + q * 8, Bw + (brow0 + r) * KD + ke + kkg * 8);
    }
  };

  const int sxA = fq ^ (fm & 7);        // read slot xor (per-lane const),
  // full slot for half h: (h*4+fq)^(fm&7) = computed per h below.

  auto compute = [&](const uint16_t* CA, const uint16_t* CB) {
#pragma unroll
    for (int h = 0; h < 2; ++h) {
      bf16x8 af[4], bfr[4];
#pragma unroll
      for (int mt = 0; mt < 4; ++mt) {
        int row = wm * 64 + mt * 16 + fm;
        int sl = (h * 4 + fq) ^ (fm & 7);
        af[mt] = *(const bf16x8*)(const void*)(CA + row * 64 + sl * 8);
      }
#pragma unroll
      for (int nt = 0; nt < 4; ++nt) {
        int row = wn * 64 + nt * 16 + fm;
        int sl = (h * 4 + fq) ^ (fm & 7);
        bfr[nt] = *(const bf16x8*)(const void*)(CB + row * 64 + sl * 8);
      }
#pragma unroll
      for (int mt = 0; mt < 4; ++mt)
#pragma unroll
        for (int nt = 0; nt < 4; ++nt)
          acc[mt][nt] = __builtin_amdgcn_mfma_f32_16x16x32_bf16(
              af[mt], bfr[nt], acc[mt][nt], 0, 0, 0);
    }
  };
  (void)sxA;

  constexpr int NT = KD / 64;           // 4 (GEMM1) or 16 (GEMM2), even

  // Prologue: stage tile 0 into buf0; barrier drains vmcnt.
  stage(A0, B0, 0);
  __syncthreads();

#pragma unroll 1
  for (int t = 0; t < NT; t += 2) {
    // phase even: stage t+1 -> buf1, compute buf0
    stage(A1, B1, (t + 1) & (NT - 1));
    compute(A0, B0);
    __syncthreads();                    // drains vmcnt(0): buf1 ready
    // phase odd: stage t+2 (wraps harmlessly on last iter) -> buf0
    stage(A0, B0, (t + 2) & (NT - 1));
    compute(A1, B1);
    __syncthreads();
  }

  if (EPI == 0) {
    // fast GELU -> h, row-major (rows x 1024) bf16.
    // D layout: col=lane&15, row=fq*4+r (m89/m91 verified).
#pragma unroll
    for (int mt = 0; mt < 4; ++mt) {
      const size_t rb = arow0 + wm * 64 + mt * 16 + fq * 4;
#pragma unroll
      for (int nt = 0; nt < 4; ++nt) {
        const size_t n2 = brow0 + wn * 64 + nt * 16 + fm;
#pragma unroll
        for (int r = 0; r < 4; ++r)
          Cb16[(rb + r) * 1024 + n2] = f2bf(fast_gelu(acc[mt][nt][r]));
      }
    }
  } else {
    // Transpose through LDS -> pixel-contiguous NCHW fp32 stores + residual.
    __syncthreads();
#pragma unroll
    for (int mt = 0; mt < 4; ++mt) {
      int mbase = wm * 64 + mt * 16 + fq * 4;     // pixel within tile
#pragma unroll
      for (int nt = 0; nt < 4; ++nt) {
        int nn = wn * 64 + nt * 16 + fm;          // channel within tile
#pragma unroll
        for (int r = 0; r < 4; ++r)
          lds[nn * 130 + mbase + r] = f2bf(acc[mt][nt][r]);
      }
    }
    __syncthreads();
    const int pl0 = tid & 31;
    const int cw = tid >> 5;
#pragma unroll
    for (int it = 0; it < 16; ++it) {
      int ch = cw + it * 8;                        // channel within tile
      int cgl = (int)brow0 + ch;                   // global channel
#pragma unroll
      for (int e = 0; e < 4; ++e) {
        int pl = pl0 + e * 32;                     // pixel within tile
        uint32_t pg = (uint32_t)chunk_pix0 + by * 128u + (uint32_t)pl;
        uint32_t bimg = pg / 3136u;
        uint32_t rem = pg - bimg * 3136u;
        size_t addr = ((size_t)bimg * 256 + cgl) * 3136 + rem;
        Cf32[addr] = bf2f(lds[ch * 130 + pl]) + Xres[addr];
      }
    }
  }
}

// ---------------------------------------------------------------------------
// Launch: cvt weights -> neocell -> y1 (ws). Then (single pass if ws allows):
//   GEMM1 (K=256)  y1 @ fc1^T -> gelu -> h (bf16, ws)
//   GEMM2 (K=1024) h @ fc2^T + x -> out (fp32 NCHW)
// ---------------------------------------------------------------------------
extern "C" void kernel_launch(void* const* d_in, const int* in_sizes, int n_in,
                              void* d_out, int out_size, void* d_ws,
                              size_t ws_size, hipStream_t stream)
{
  const float* x   = (const float*)d_in[0];
  const float* wa1 = (const float*)d_in[1];
  const float* wb1 = (const float*)d_in[2];
  const float* wa2 = (const float*)d_in[3];
  const float* wb2 = (const float*)d_in[4];
  const float* bnw = (const float*)d_in[5];
  const float* bnb = (const float*)d_in[6];
  const float* bnm = (const float*)d_in[7];
  const float* bnv = (const float*)d_in[8];
  const float* fc1 = (const float*)d_in[9];
  const float* fc2 = (const float*)d_in[10];
  float* out = (float*)d_out;

  uint16_t* fc1b = (uint16_t*)d_ws;                 // 512 KB
  uint16_t* fc2b = fc1b + 262144;                   // 512 KB
  uint16_t* y1 = fc2b + 262144;                     // 51.4 MB
  const size_t y1_elems = (size_t)100352 * 256;
  uint16_t* h = y1 + y1_elems;

  const long tiles_total = 784;                     // 100352 / 128
  const size_t fixed_bytes = (size_t)262144 * 4 + y1_elems * 2;
  long tiles_chunk = 1;
  if (ws_size > fixed_bytes + 262144) {
    tiles_chunk = (long)((ws_size - fixed_bytes) / (128ul * 1024ul * 2ul));
    if (tiles_chunk > tiles_total) tiles_chunk = tiles_total;
    if (tiles_chunk < 1) tiles_chunk = 1;
  }

  cvt_weights_kernel<<<512, 256, 0, stream>>>(fc1, fc2, fc1b, fc2b);
  neocell_bn_kernel<<<dim3(14, 32, 4), 128, 0, stream>>>(
      x, wa1, wb1, wa2, wb2, bnw, bnb, bnm, bnv, y1);

  for (long t0 = 0; t0 < tiles_total; t0 += tiles_chunk) {
    long T = tiles_total - t0;
    if (T > tiles_chunk) T = tiles_chunk;
    gemm_bt_kernel<256, 0><<<dim3(8, (uint32_t)T), 256, 0, stream>>>(
        y1 + (size_t)t0 * 128 * 256, fc1b, h, nullptr, nullptr, 0);
    gemm_bt_kernel<1024, 1><<<dim3(2, (uint32_t)T), 256, 0, stream>>>(
        h, fc2b, nullptr, out, x, (int)(t0 * 128));
  }
}